// Round 3
// baseline (778.365 us; speedup 1.0000x reference)
//
#include <hip/hip_runtime.h>
#include <hip/hip_bf16.h>
#include <cstdint>
#include <cstddef>

// NaryTreeLSTM bottom-up level sweep, fully fused per level:
// one kernel computes h,c for a level directly (GEMM + gates in-register).
//
// Wbig [1280 x 768] bf16, rows: [0,256)=i [256,512)=o [512,768)=u
// [768,1024)=f_left=[W_f|U_f0|0] [1024,1280)=f_right=[W_f|0|U_f1].
// A_virtual[m] = [x_m (256) | h_l (256) | h_r (256)], h stored bf16, c fp32.
//
// fused_level<NG>: block = 256 thr = 4 waves; tile = 64 rows x 128 d's x NG gates.
// blockIdx.x = d-half (0/1), blockIdx.y = row block. Wave w owns d-slice of 32:
// all NG gate accumulators for (64 rows x 32 d) live in that wave's registers,
// so the LSTM cell epilogue is wave-local. NG=3 for leaves (no f gates).

typedef __attribute__((ext_vector_type(8))) __bf16 bf16x8;
typedef __attribute__((ext_vector_type(4))) float floatx4;

__device__ __forceinline__ float sigf(float x) { return 1.0f / (1.0f + __expf(-x)); }

__device__ __forceinline__ void load_lds16(const void* g, void* l) {
    __builtin_amdgcn_global_load_lds(
        (const __attribute__((address_space(1))) unsigned int*)g,
        (__attribute__((address_space(3))) unsigned int*)l, 16, 0, 0);
}

__global__ void pack_weights(const float* __restrict__ Wi, const float* __restrict__ bi, const float* __restrict__ Ui,
                             const float* __restrict__ Wo, const float* __restrict__ bo, const float* __restrict__ Uo,
                             const float* __restrict__ Wu, const float* __restrict__ bu, const float* __restrict__ Uu,
                             const float* __restrict__ Wf, const float* __restrict__ bf, const float* __restrict__ Uf,
                             __hip_bfloat16* __restrict__ Wbig, float* __restrict__ biasbig)
{
    int j = blockIdx.x;    // 0..1279 output row
    int k = threadIdx.x;   // 0..255
    const float *W, *b, *U0, *U1;
    int d;
    if (j < 256)        { W = Wi; b = bi; U0 = Ui;       U1 = Ui + 65536; d = j; }
    else if (j < 512)   { W = Wo; b = bo; U0 = Uo;       U1 = Uo + 65536; d = j - 256; }
    else if (j < 768)   { W = Wu; b = bu; U0 = Uu;       U1 = Uu + 65536; d = j - 512; }
    else if (j < 1024)  { W = Wf; b = bf; U0 = Uf;       U1 = nullptr;    d = j - 768; }
    else                { W = Wf; b = bf; U0 = nullptr;  U1 = Uf + 65536; d = j - 1024; }
    __hip_bfloat16* row = Wbig + (size_t)j * 768;
    row[k]       = __float2bfloat16(W[d * 256 + k]);
    row[256 + k] = __float2bfloat16(U0 ? U0[d * 256 + k] : 0.0f);
    row[512 + k] = __float2bfloat16(U1 ? U1[d * 256 + k] : 0.0f);
    if (k == 0) biasbig[j] = b[d];
}

__global__ void convert_f32_bf16(const float* __restrict__ in, __hip_bfloat16* __restrict__ out, int n4)
{
    int i = blockIdx.x * 256 + threadIdx.x;
    if (i >= n4) return;
    float4 v = ((const float4*)in)[i];
    __hip_bfloat16 tmp[4];
    tmp[0] = __float2bfloat16(v.x);
    tmp[1] = __float2bfloat16(v.y);
    tmp[2] = __float2bfloat16(v.z);
    tmp[3] = __float2bfloat16(v.w);
    *(ushort4*)(out + (size_t)i * 4) = *(const ushort4*)tmp;
}

template<int NG>  // 5 = internal (Kd=768), 3 = leaf (Kd=256, c = i*u)
__global__ __launch_bounds__(256, 2) void fused_level(
    const __hip_bfloat16* __restrict__ embX,   // [.][256]
    const __hip_bfloat16* __restrict__ hprev,  // [.][512] (children pairs)
    const float* __restrict__ cprev,           // [.][512]
    const __hip_bfloat16* __restrict__ Wbig,   // [1280][768]
    const float* __restrict__ biasbig,         // [1280]
    __hip_bfloat16* __restrict__ hout,         // [.][256]
    float* __restrict__ cout,                  // [.][256]
    int M)
{
    constexpr int Kd = (NG == 3) ? 256 : 768;
    __shared__ __hip_bfloat16 sA[64 * 32];
    __shared__ __hip_bfloat16 sB[NG * 128 * 32];
    const int t = threadIdx.x;
    const int dc = blockIdx.x;            // d-half: d in [dc*128, dc*128+128)
    const int bm0 = blockIdx.y * 64;
    const int lane = t & 63;
    const int w = t >> 6;                 // wave 0..3, owns d-slice w*32
    const int lrow = lane & 15;
    const int q = lane >> 4;

    floatx4 acc[NG][2][4];
    #pragma unroll
    for (int g = 0; g < NG; ++g)
        #pragma unroll
        for (int dt = 0; dt < 2; ++dt)
            #pragma unroll
            for (int mt = 0; mt < 4; ++mt) acc[g][dt][mt] = (floatx4){0.f, 0.f, 0.f, 0.f};

    for (int k0 = 0; k0 < Kd; k0 += 32) {
        // Stage A: 64 rows x 32 k (4 KB), one 16B chunk per thread.
        {
            int r = t >> 2, kc = t & 3;
            int gm = bm0 + r;
            const __hip_bfloat16* src = (k0 < 256)
                ? embX  + (size_t)gm * 256 + k0 + kc * 8
                : hprev + (size_t)gm * 512 + (k0 - 256) + kc * 8;
            load_lds16(src, &sA[t * 8]);
        }
        // Stage B: NG*128 rows x 32 k; chunk cid -> row=cid>>2, kc=cid&3.
        // Global row j = g*256 + dc*128 + r  (g = row>>7, r = row&127).
        #pragma unroll
        for (int rep = 0; rep < NG * 2; ++rep) {
            int cid = rep * 256 + t;
            int row = cid >> 2, kc = cid & 3;
            int g = row >> 7, r = row & 127;
            load_lds16(Wbig + (size_t)(g * 256 + dc * 128 + r) * 768 + k0 + kc * 8,
                       &sB[cid * 8]);
        }
        __syncthreads();

        bf16x8 af[4];
        #pragma unroll
        for (int mt = 0; mt < 4; ++mt)
            af[mt] = *(const bf16x8*)&sA[(mt * 16 + lrow) * 32 + q * 8];
        #pragma unroll
        for (int g = 0; g < NG; ++g)
            #pragma unroll
            for (int dt = 0; dt < 2; ++dt) {
                bf16x8 bfrag = *(const bf16x8*)&sB[(g * 128 + w * 32 + dt * 16 + lrow) * 32 + q * 8];
                #pragma unroll
                for (int mt = 0; mt < 4; ++mt)
                    acc[g][dt][mt] = __builtin_amdgcn_mfma_f32_16x16x32_bf16(af[mt], bfrag, acc[g][dt][mt], 0, 0, 0);
            }
        __syncthreads();
    }

    // Epilogue: wave-local LSTM cell. C/D layout: col=lane&15, row=q*4+reg.
    const int d0 = dc * 128 + w * 32;
    #pragma unroll
    for (int dt = 0; dt < 2; ++dt) {
        const int d = d0 + dt * 16 + lrow;
        const float bi_ = biasbig[d];
        const float bo_ = biasbig[256 + d];
        const float bu_ = biasbig[512 + d];
        const float bf_ = (NG == 5) ? biasbig[768 + d] : 0.0f;  // b_f (same for f_l, f_r)
        #pragma unroll
        for (int mt = 0; mt < 4; ++mt) {
            #pragma unroll
            for (int rr = 0; rr < 4; ++rr) {
                const int m = bm0 + mt * 16 + q * 4 + rr;
                if (m >= M) continue;
                float iv = sigf(acc[0][dt][mt][rr] + bi_);
                float ov = sigf(acc[1][dt][mt][rr] + bo_);
                float uv = tanhf(acc[2][dt][mt][rr] + bu_);
                float c;
                if (NG == 5) {
                    float fl = sigf(acc[3][dt][mt][rr] + bf_);
                    float fr = sigf(acc[4][dt][mt][rr] + bf_);
                    c = iv * uv + fl * cprev[(size_t)m * 512 + d]
                                + fr * cprev[(size_t)m * 512 + 256 + d];
                } else {
                    c = iv * uv;
                }
                cout[(size_t)m * 256 + d] = c;
                hout[(size_t)m * 256 + d] = __float2bfloat16(ov * tanhf(c));
            }
        }
    }
}

__global__ void write_out(const __hip_bfloat16* __restrict__ h, const float* __restrict__ c,
                          float* __restrict__ out)
{
    int t = threadIdx.x; // 256
    out[t] = __bfloat162float(h[t]);
    out[256 + t] = c[t];
}

extern "C" void kernel_launch(void* const* d_in, const int* in_sizes, int n_in,
                              void* d_out, int out_size, void* d_ws, size_t ws_size,
                              hipStream_t stream)
{
    const float* emb = (const float*)d_in[0];
    const float* Wi  = (const float*)d_in[1];
    const float* bi  = (const float*)d_in[2];
    const float* Ui  = (const float*)d_in[3];
    const float* Wo  = (const float*)d_in[4];
    const float* bo  = (const float*)d_in[5];
    const float* Uo  = (const float*)d_in[6];
    const float* Wu  = (const float*)d_in[7];
    const float* bu  = (const float*)d_in[8];
    const float* Uu  = (const float*)d_in[9];
    const float* Wf  = (const float*)d_in[10];
    const float* bf  = (const float*)d_in[11];
    const float* Uf  = (const float*)d_in[12];

    char* p = (char*)d_ws;
    __hip_bfloat16* Wbig = (__hip_bfloat16*)p;  p += (size_t)1280 * 768 * 2;
    float* biasbig       = (float*)p;           p += (size_t)1280 * 4;
    __hip_bfloat16* embB = (__hip_bfloat16*)p;  p += (size_t)65535 * 256 * 2;
    __hip_bfloat16* hbuf = (__hip_bfloat16*)p;  p += (size_t)65535 * 256 * 2;
    float* cbuf          = (float*)p;           // 65535*256*4

    pack_weights<<<1280, 256, 0, stream>>>(Wi, bi, Ui, Wo, bo, Uo, Wu, bu, Uu, Wf, bf, Uf,
                                           Wbig, biasbig);
    convert_f32_bf16<<<(65535 * 256 / 4 + 255) / 256, 256, 0, stream>>>(emb, embB, 65535 * 256 / 4);

    // Leaves: level 15, n = 32768, start = 32767. 3 gates, Kd=256.
    {
        const int n = 32768, start = n - 1;
        fused_level<3><<<dim3(2, n / 64), 256, 0, stream>>>(
            embB + (size_t)start * 256, hbuf, cbuf, Wbig, biasbig,
            hbuf + (size_t)start * 256, cbuf + (size_t)start * 256, n);
    }

    // Internal levels, bottom-up. 5 gates, Kd=768.
    for (int l = 14; l >= 0; --l) {
        const int n = 1 << l;
        const int start = n - 1;
        const int startc = 2 * n - 1;
        fused_level<5><<<dim3(2, (n + 63) / 64), 256, 0, stream>>>(
            embB + (size_t)start * 256,
            hbuf + (size_t)startc * 256,
            cbuf + (size_t)startc * 256,
            Wbig, biasbig,
            hbuf + (size_t)start * 256, cbuf + (size_t)start * 256, n);
    }

    write_out<<<1, 256, 0, stream>>>(hbuf, cbuf, (float*)d_out);
}

// Round 4
// 521.144 us; speedup vs baseline: 1.4936x; 1.4936x over previous
//
#include <hip/hip_runtime.h>
#include <hip/hip_bf16.h>
#include <cstdint>
#include <cstddef>

// NaryTreeLSTM bottom-up level sweep, fused GEMM+gates per level.
//
// 3-phase K-split (no structural zeros, W_f x computed once):
//   phase 0: k = x (Kd 256), slots {W_i, W_o, W_u, W_f}
//   phase 1: k = h_l,        slots {U_i0, U_o0, U_u0, U_f0}
//   phase 2: k = h_r,        slots {U_i1, U_o1, U_u1, U_f1}
// Slots 0-2 (i,o,u) accumulate across phases; slot 3 (f) kept per-phase:
//   f_l = sig(fx + f_p1 + b_f), f_r = sig(fx + f_p2 + b_f).
//
// Wpack[12][256][256] bf16 (mat = p*4+s), biasv[4][256] fp32.
// Block: 64 rows x 64 d x 4 slots; 4 waves, wave w owns d-slice w*16.
// Grid: dim3(4, ceil(M/64)). Leaf: <3 slots, 1 phase>, c = i*u.

typedef __attribute__((ext_vector_type(8))) __bf16 bf16x8;
typedef __attribute__((ext_vector_type(4))) float floatx4;

__device__ __forceinline__ float sigf(float x) { return 1.0f / (1.0f + __expf(-x)); }

__device__ __forceinline__ void load_lds16(const void* g, void* l) {
    __builtin_amdgcn_global_load_lds(
        (const __attribute__((address_space(1))) unsigned int*)g,
        (__attribute__((address_space(3))) unsigned int*)l, 16, 0, 0);
}

__global__ void pack_weights(const float* __restrict__ Wi, const float* __restrict__ bi, const float* __restrict__ Ui,
                             const float* __restrict__ Wo, const float* __restrict__ bo, const float* __restrict__ Uo,
                             const float* __restrict__ Wu, const float* __restrict__ bu, const float* __restrict__ Uu,
                             const float* __restrict__ Wf, const float* __restrict__ bf, const float* __restrict__ Uf,
                             __hip_bfloat16* __restrict__ Wpack, float* __restrict__ biasv)
{
    int m = blockIdx.x;   // 0..11 = p*4+s
    int d = blockIdx.y;   // 0..255
    int k = threadIdx.x;  // 0..255
    const float* tbl[12] = {Wi, Wo, Wu, Wf,
                            Ui, Uo, Uu, Uf,
                            Ui + 65536, Uo + 65536, Uu + 65536, Uf + 65536};
    Wpack[((size_t)m * 256 + d) * 256 + k] = __float2bfloat16(tbl[m][d * 256 + k]);
    if (m < 4 && k == 0) {
        const float* bt[4] = {bi, bo, bu, bf};
        biasv[m * 256 + d] = bt[m][d];
    }
}

__global__ void convert_f32_bf16(const float* __restrict__ in, __hip_bfloat16* __restrict__ out, int n4)
{
    int i = blockIdx.x * 256 + threadIdx.x;
    if (i >= n4) return;
    float4 v = ((const float4*)in)[i];
    __hip_bfloat16 tmp[4];
    tmp[0] = __float2bfloat16(v.x);
    tmp[1] = __float2bfloat16(v.y);
    tmp[2] = __float2bfloat16(v.z);
    tmp[3] = __float2bfloat16(v.w);
    *(ushort4*)(out + (size_t)i * 4) = *(const ushort4*)tmp;
}

// NS = B-slots per phase (4 internal, 3 leaf), NP = phases (3 internal, 1 leaf)
template<int NS, int NP>
__global__ __launch_bounds__(256) void fused_level(
    const __hip_bfloat16* __restrict__ embX,   // [.][256]
    const __hip_bfloat16* __restrict__ hprev,  // [.][512] (children pairs)
    const float* __restrict__ cprev,           // [.][512]
    const __hip_bfloat16* __restrict__ Wpack,  // [12][256][256]
    const float* __restrict__ biasv,           // [4][256]
    __hip_bfloat16* __restrict__ hout,         // [.][256]
    float* __restrict__ cout,                  // [.][256]
    int M)
{
    __shared__ __hip_bfloat16 sA[64 * 32];
    __shared__ __hip_bfloat16 sB[NS * 64 * 32];
    const int t = threadIdx.x;
    const int dchunk = blockIdx.x;        // d in [dchunk*64, +64)
    const int bm0 = blockIdx.y * 64;
    const int lane = t & 63;
    const int w = t >> 6;                 // wave owns d-slice w*16
    const int lrow = lane & 15;
    const int q = lane >> 4;

    floatx4 accS[3][4];                   // i,o,u — accumulate across phases
    floatx4 accF[NP][4];                  // f — per phase (x, h_l, h_r)
    #pragma unroll
    for (int s = 0; s < 3; ++s)
        #pragma unroll
        for (int mt = 0; mt < 4; ++mt) accS[s][mt] = (floatx4){0.f, 0.f, 0.f, 0.f};
    #pragma unroll
    for (int p = 0; p < NP; ++p)
        #pragma unroll
        for (int mt = 0; mt < 4; ++mt) accF[p][mt] = (floatx4){0.f, 0.f, 0.f, 0.f};

    #pragma unroll
    for (int p = 0; p < NP; ++p) {
        const __hip_bfloat16* Abase = (p == 0) ? embX : hprev;
        const int astride = (p == 0) ? 256 : 512;
        const int aoff = (p == 0) ? 0 : (p - 1) * 256;
        for (int kk = 0; kk < 8; ++kk) {
            const int k0 = kk * 32;
            // Stage A: 64 rows x 32 k (4 KB), one 16B chunk/thread.
            {
                int r = t >> 2, kc = t & 3;
                load_lds16(Abase + (size_t)(bm0 + r) * astride + aoff + k0 + kc * 8,
                           &sA[t * 8]);
            }
            // Stage B: NS*64 d-rows x 32 k, NS chunks/thread.
            #pragma unroll
            for (int rep = 0; rep < NS; ++rep) {
                int cid = rep * 256 + t;
                int row = cid >> 2, kc = cid & 3;
                int s = row >> 6, r = row & 63;
                load_lds16(Wpack + (size_t)((p * 4 + s) * 256 + dchunk * 64 + r) * 256 + k0 + kc * 8,
                           &sB[cid * 8]);
            }
            __syncthreads();

            bf16x8 af[4];
            #pragma unroll
            for (int mt = 0; mt < 4; ++mt)
                af[mt] = *(const bf16x8*)&sA[(mt * 16 + lrow) * 32 + q * 8];
            #pragma unroll
            for (int s = 0; s < NS; ++s) {
                bf16x8 bfrag = *(const bf16x8*)&sB[(s * 64 + w * 16 + lrow) * 32 + q * 8];
                if (s < 3) {
                    #pragma unroll
                    for (int mt = 0; mt < 4; ++mt)
                        accS[s][mt] = __builtin_amdgcn_mfma_f32_16x16x32_bf16(af[mt], bfrag, accS[s][mt], 0, 0, 0);
                } else {
                    #pragma unroll
                    for (int mt = 0; mt < 4; ++mt)
                        accF[p][mt] = __builtin_amdgcn_mfma_f32_16x16x32_bf16(af[mt], bfrag, accF[p][mt], 0, 0, 0);
                }
            }
            __syncthreads();
        }
    }

    // Epilogue (wave-local). C/D layout: col=lane&15, row=q*4+reg.
    const int d = dchunk * 64 + w * 16 + lrow;
    const float bI = biasv[d];
    const float bO = biasv[256 + d];
    const float bU = biasv[512 + d];
    const float bF = (NS == 4) ? biasv[768 + d] : 0.0f;
    #pragma unroll
    for (int mt = 0; mt < 4; ++mt) {
        #pragma unroll
        for (int rr = 0; rr < 4; ++rr) {
            const int m = bm0 + mt * 16 + q * 4 + rr;
            if (m >= M) continue;
            float iv = sigf(accS[0][mt][rr] + bI);
            float ov = sigf(accS[1][mt][rr] + bO);
            float uv = tanhf(accS[2][mt][rr] + bU);
            float c;
            if (NS == 4) {
                float fx = accF[0][mt][rr];
                float fl = sigf(fx + accF[1][mt][rr] + bF);
                float fr = sigf(fx + accF[2][mt][rr] + bF);
                c = iv * uv + fl * cprev[(size_t)m * 512 + d]
                            + fr * cprev[(size_t)m * 512 + 256 + d];
            } else {
                c = iv * uv;
            }
            cout[(size_t)m * 256 + d] = c;
            hout[(size_t)m * 256 + d] = __float2bfloat16(ov * tanhf(c));
        }
    }
}

__global__ void write_out(const __hip_bfloat16* __restrict__ h, const float* __restrict__ c,
                          float* __restrict__ out)
{
    int t = threadIdx.x; // 256
    out[t] = __bfloat162float(h[t]);
    out[256 + t] = c[t];
}

extern "C" void kernel_launch(void* const* d_in, const int* in_sizes, int n_in,
                              void* d_out, int out_size, void* d_ws, size_t ws_size,
                              hipStream_t stream)
{
    const float* emb = (const float*)d_in[0];
    const float* Wi  = (const float*)d_in[1];
    const float* bi  = (const float*)d_in[2];
    const float* Ui  = (const float*)d_in[3];
    const float* Wo  = (const float*)d_in[4];
    const float* bo  = (const float*)d_in[5];
    const float* Uo  = (const float*)d_in[6];
    const float* Wu  = (const float*)d_in[7];
    const float* bu  = (const float*)d_in[8];
    const float* Uu  = (const float*)d_in[9];
    const float* Wf  = (const float*)d_in[10];
    const float* bf  = (const float*)d_in[11];
    const float* Uf  = (const float*)d_in[12];

    char* p = (char*)d_ws;
    __hip_bfloat16* Wpack = (__hip_bfloat16*)p;  p += (size_t)12 * 256 * 256 * 2;
    float* biasv          = (float*)p;           p += (size_t)4 * 256 * 4;
    __hip_bfloat16* embB  = (__hip_bfloat16*)p;  p += (size_t)65535 * 256 * 2;
    __hip_bfloat16* hbuf  = (__hip_bfloat16*)p;  p += (size_t)65535 * 256 * 2;
    float* cbuf           = (float*)p;           // 65535*256*4

    pack_weights<<<dim3(12, 256), 256, 0, stream>>>(Wi, bi, Ui, Wo, bo, Uo, Wu, bu, Uu, Wf, bf, Uf,
                                                    Wpack, biasv);
    convert_f32_bf16<<<(65535 * 256 / 4 + 255) / 256, 256, 0, stream>>>(emb, embB, 65535 * 256 / 4);

    // Leaves: level 15, n = 32768. 1 phase, 3 slots, c = i*u.
    {
        const int n = 32768, start = n - 1;
        fused_level<3, 1><<<dim3(4, n / 64), 256, 0, stream>>>(
            embB + (size_t)start * 256, nullptr, nullptr, Wpack, biasv,
            hbuf + (size_t)start * 256, cbuf + (size_t)start * 256, n);
    }

    // Internal levels, bottom-up. 3 phases, 4 slots.
    for (int l = 14; l >= 0; --l) {
        const int n = 1 << l;
        const int start = n - 1;
        const int startc = 2 * n - 1;
        fused_level<4, 3><<<dim3(4, (n + 63) / 64), 256, 0, stream>>>(
            embB + (size_t)start * 256,
            hbuf + (size_t)startc * 256,
            cbuf + (size_t)startc * 256,
            Wpack, biasv,
            hbuf + (size_t)start * 256, cbuf + (size_t)start * 256, n);
    }

    write_out<<<1, 256, 0, stream>>>(hbuf, cbuf, (float*)d_out);
}